// Round 1
// baseline (117.404 us; speedup 1.0000x reference)
//
#include <hip/hip_runtime.h>
#include <cstdint>

static constexpr int BATCH = 64;
static constexpr int NPB   = 512 * 512;   // elements per batch = 262144
static constexpr int NB    = 256;         // histogram bins

// d_ws layout in 32-bit words:
static constexpr int W_MINK = 0;                   // 64 uint keys (monotone float->uint)
static constexpr int W_MAXK = 64;                  // 64 uint keys
static constexpr int W_HIST = 128;                 // 64*256 uint
static constexpr int W_THR  = 128 + BATCH * NB;    // 64 floats (prob-space threshold)
static constexpr int W_CNT  = W_THR + 64;          // nb[64], nt[64], ni[64] uint
static constexpr int W_END  = W_CNT + 3 * 64;      // 16768 words ~ 65.5 KB

__device__ __forceinline__ uint32_t fkey(float f) {
  uint32_t u = __float_as_uint(f);
  return u ^ ((u & 0x80000000u) ? 0xFFFFFFFFu : 0x80000000u);
}
__device__ __forceinline__ float funkey(uint32_t k) {
  uint32_t u = (k & 0x80000000u) ? (k ^ 0x80000000u) : ~k;
  return __uint_as_float(u);
}
__device__ __forceinline__ float sigmoidf(float v) {
  if (v >= 0.0f) return 1.0f / (1.0f + expf(-v));
  float e = expf(v);
  return e / (1.0f + e);
}

__global__ __launch_bounds__(256) void k_init(uint32_t* __restrict__ ws) {
  int i = blockIdx.x * 256 + threadIdx.x;
  if (i < W_END) ws[i] = (i < 64) ? 0xFFFFFFFFu : 0u;
}

// 16 blocks per batch, 256 threads, float4 loads; min/max of raw logits.
__global__ __launch_bounds__(256) void k_minmax(const float* __restrict__ x,
                                                uint32_t* __restrict__ ws) {
  const int b = blockIdx.x >> 4;
  const int blk = blockIdx.x & 15;
  const int t = threadIdx.x;
  const float4* p = reinterpret_cast<const float4*>(x + (size_t)b * NPB + (size_t)blk * (NPB / 16));
  float mn = INFINITY, mx = -INFINITY;
#pragma unroll
  for (int i = 0; i < 16; ++i) {
    float4 v = p[i * 256 + t];
    mn = fminf(mn, fminf(fminf(v.x, v.y), fminf(v.z, v.w)));
    mx = fmaxf(mx, fmaxf(fmaxf(v.x, v.y), fmaxf(v.z, v.w)));
  }
  for (int off = 32; off; off >>= 1) {
    mn = fminf(mn, __shfl_down(mn, off));
    mx = fmaxf(mx, __shfl_down(mx, off));
  }
  __shared__ float smn[4], smx[4];
  if ((t & 63) == 0) { smn[t >> 6] = mn; smx[t >> 6] = mx; }
  __syncthreads();
  if (t == 0) {
    mn = fminf(fminf(smn[0], smn[1]), fminf(smn[2], smn[3]));
    mx = fmaxf(fmaxf(smx[0], smx[1]), fmaxf(smx[2], smx[3]));
    atomicMin(&ws[W_MINK + b], fkey(mn));
    atomicMax(&ws[W_MAXK + b], fkey(mx));
  }
}

// 16 blocks per batch; per-block LDS histogram then one global atomicAdd per bin.
__global__ __launch_bounds__(256) void k_hist(const float* __restrict__ x,
                                              uint32_t* __restrict__ ws) {
  __shared__ uint32_t h[NB];
  const int t = threadIdx.x;
  h[t] = 0;
  const int b = blockIdx.x >> 4;
  const int blk = blockIdx.x & 15;
  const float pmin = sigmoidf(funkey(ws[W_MINK + b]));
  const float pmax = sigmoidf(funkey(ws[W_MAXK + b]));
  const float span = pmax - pmin;
  const float scale = (span > 0.0f) ? (256.0f / span) : 0.0f;
  __syncthreads();
  const float4* p = reinterpret_cast<const float4*>(x + (size_t)b * NPB + (size_t)blk * (NPB / 16));
#pragma unroll 4
  for (int i = 0; i < 16; ++i) {
    float4 v = p[i * 256 + t];
#define PUT(c) { int idx = (int)((sigmoidf(c) - pmin) * scale); \
                 idx = idx < 0 ? 0 : (idx > 255 ? 255 : idx);   \
                 atomicAdd(&h[idx], 1u); }
    PUT(v.x) PUT(v.y) PUT(v.z) PUT(v.w)
#undef PUT
  }
  __syncthreads();
  if (h[t]) atomicAdd(&ws[W_HIST + b * NB + t], h[t]);
}

// One block per batch; thread 0 does the serial Otsu scan in np.cumsum order.
__global__ __launch_bounds__(64) void k_otsu(uint32_t* __restrict__ ws) {
  __shared__ float histf[NB], w2s[NB], s2s[NB];
  const int b = blockIdx.x;
  const int t = threadIdx.x;
  for (int i = t; i < NB; i += 64) histf[i] = (float)ws[W_HIST + b * NB + i];
  __syncthreads();
  if (t == 0) {
    const float pmin = sigmoidf(funkey(ws[W_MINK + b]));
    const float pmax = sigmoidf(funkey(ws[W_MAXK + b]));
    const float span = pmax - pmin;
    const float binw = span / 256.0f;  // exact (pow2 divide), matches span/NBINS
    // backward cumsums (== cumsum of reversed arrays, serial order)
    float w = 0.0f, s = 0.0f;
    for (int k = NB - 1; k >= 0; --k) {
      const float h = histf[k];
      const float c = pmin + ((float)k + 0.5f) * binw;
      w += h;
      s += h * c;
      w2s[k] = w; s2s[k] = s;
    }
    // forward cumsums + argmax of var12 (first occurrence wins: strict >)
    float w1 = 0.0f, s1 = 0.0f, best = -INFINITY;
    int bi = 0;
    for (int k = 0; k < NB - 1; ++k) {
      const float h = histf[k];
      const float c = pmin + ((float)k + 0.5f) * binw;
      w1 += h; s1 += h * c;
      const float m1 = s1 / w1;
      const float m2 = s2s[k + 1] / w2s[k + 1];
      const float d = m1 - m2;
      const float v = (w1 * w2s[k + 1]) * (d * d);  // match (w1*w2)*(d**2) order
      if (v > best) { best = v; bi = k; }
    }
    reinterpret_cast<float*>(ws)[W_THR + b] = pmin + ((float)bi + 0.5f) * binw;
  }
}

// 32 blocks per batch; exact integer counts of binary / target / intersection.
__global__ __launch_bounds__(256) void k_count(const float* __restrict__ x,
                                               const float* __restrict__ tg,
                                               uint32_t* __restrict__ ws) {
  const int b = blockIdx.x >> 5;
  const int blk = blockIdx.x & 31;
  const int t = threadIdx.x;
  const float thr = reinterpret_cast<const float*>(ws)[W_THR + b];
  const size_t base = (size_t)b * NPB + (size_t)blk * (NPB / 32);
  const float4* px = reinterpret_cast<const float4*>(x + base);
  const float4* pt = reinterpret_cast<const float4*>(tg + base);
  uint32_t nb = 0, nt = 0, ni = 0;
#pragma unroll
  for (int i = 0; i < 8; ++i) {
    float4 v = px[i * 256 + t];
    float4 w = pt[i * 256 + t];
#define ACC(a, c) { uint32_t bb = sigmoidf(a) > thr ? 1u : 0u; \
                    uint32_t tt = (c) > 0.5f ? 1u : 0u;        \
                    nb += bb; nt += tt; ni += bb & tt; }
    ACC(v.x, w.x) ACC(v.y, w.y) ACC(v.z, w.z) ACC(v.w, w.w)
#undef ACC
  }
  for (int off = 32; off; off >>= 1) {
    nb += __shfl_down(nb, off);
    nt += __shfl_down(nt, off);
    ni += __shfl_down(ni, off);
  }
  __shared__ uint32_t s[3][4];
  if ((t & 63) == 0) { int w64 = t >> 6; s[0][w64] = nb; s[1][w64] = nt; s[2][w64] = ni; }
  __syncthreads();
  if (t == 0) {
    nb = s[0][0] + s[0][1] + s[0][2] + s[0][3];
    nt = s[1][0] + s[1][1] + s[1][2] + s[1][3];
    ni = s[2][0] + s[2][1] + s[2][2] + s[2][3];
    atomicAdd(&ws[W_CNT + b], nb);
    atomicAdd(&ws[W_CNT + 64 + b], nt);
    atomicAdd(&ws[W_CNT + 128 + b], ni);
  }
}

__global__ __launch_bounds__(64) void k_final(const uint32_t* __restrict__ ws,
                                              float* __restrict__ out) {
  const int t = threadIdx.x;  // 64 = one wave, one lane per batch
  const float nb = (float)ws[W_CNT + t];
  const float nt = (float)ws[W_CNT + 64 + t];
  const float ni = (float)ws[W_CNT + 128 + t];
  const float uni = nb + nt - ni;
  float iou = (ni + 1.0f) / (uni + 1.0f);
  for (int off = 32; off; off >>= 1) iou += __shfl_down(iou, off);
  if (t == 0) out[0] = iou * (1.0f / 64.0f);
}

extern "C" void kernel_launch(void* const* d_in, const int* in_sizes, int n_in,
                              void* d_out, int out_size, void* d_ws, size_t ws_size,
                              hipStream_t stream) {
  const float* x  = (const float*)d_in[0];   // logits (64,1,512,512)
  const float* tg = (const float*)d_in[1];   // target (64,1,512,512)
  uint32_t* ws = (uint32_t*)d_ws;
  float* out = (float*)d_out;

  hipLaunchKernelGGL(k_init,   dim3((W_END + 255) / 256), dim3(256), 0, stream, ws);
  hipLaunchKernelGGL(k_minmax, dim3(BATCH * 16), dim3(256), 0, stream, x, ws);
  hipLaunchKernelGGL(k_hist,   dim3(BATCH * 16), dim3(256), 0, stream, x, ws);
  hipLaunchKernelGGL(k_otsu,   dim3(BATCH),      dim3(64),  0, stream, ws);
  hipLaunchKernelGGL(k_count,  dim3(BATCH * 32), dim3(256), 0, stream, x, tg, ws);
  hipLaunchKernelGGL(k_final,  dim3(1),          dim3(64),  0, stream, ws, out);
}

// Round 2
// 55.158 us; speedup vs baseline: 2.1285x; 2.1285x over previous
//
#include <hip/hip_runtime.h>
#include <cstdint>

static constexpr int BATCH = 64;
static constexpr int NPB   = 512 * 512;   // elements per batch
static constexpr int NCB   = 1024;        // combined bins: 512 half-bins x 2 target classes

// d_ws layout in 32-bit words:
static constexpr int W_MINK = 0;                    // 64 uint keys
static constexpr int W_MAXK = 64;                   // 64 uint keys
static constexpr int W_HIST = 128;                  // 64*1024 uint combined hist
static constexpr int W_IOU  = W_HIST + BATCH * NCB; // 64 floats (per-batch IoU)
static constexpr int W_END  = W_IOU + 64;           // 65728 words ~ 263 KB

__device__ __forceinline__ uint32_t fkey(float f) {
  uint32_t u = __float_as_uint(f);
  return u ^ ((u & 0x80000000u) ? 0xFFFFFFFFu : 0x80000000u);
}
__device__ __forceinline__ float funkey(uint32_t k) {
  uint32_t u = (k & 0x80000000u) ? (k ^ 0x80000000u) : ~k;
  return __uint_as_float(u);
}
__device__ __forceinline__ float sigmoidf(float v) {
  if (v >= 0.0f) return 1.0f / (1.0f + expf(-v));
  float e = expf(v);
  return e / (1.0f + e);
}

__global__ __launch_bounds__(256) void k_init(uint32_t* __restrict__ ws) {
  int i = blockIdx.x * 256 + threadIdx.x;
  if (i < W_END) ws[i] = (i < 64) ? 0xFFFFFFFFu : 0u;
}

// 16 blocks per batch: min/max of raw logits (sigmoid is monotone).
__global__ __launch_bounds__(256) void k_minmax(const float* __restrict__ x,
                                                uint32_t* __restrict__ ws) {
  const int b = blockIdx.x >> 4;
  const int blk = blockIdx.x & 15;
  const int t = threadIdx.x;
  const float4* p = reinterpret_cast<const float4*>(x + (size_t)b * NPB + (size_t)blk * (NPB / 16));
  float mn = INFINITY, mx = -INFINITY;
#pragma unroll
  for (int i = 0; i < 16; ++i) {
    float4 v = p[i * 256 + t];
    mn = fminf(mn, fminf(fminf(v.x, v.y), fminf(v.z, v.w)));
    mx = fmaxf(mx, fmaxf(fmaxf(v.x, v.y), fmaxf(v.z, v.w)));
  }
  for (int off = 32; off; off >>= 1) {
    mn = fminf(mn, __shfl_down(mn, off));
    mx = fmaxf(mx, __shfl_down(mx, off));
  }
  __shared__ float smn[4], smx[4];
  if ((t & 63) == 0) { smn[t >> 6] = mn; smx[t >> 6] = mx; }
  __syncthreads();
  if (t == 0) {
    mn = fminf(fminf(smn[0], smn[1]), fminf(smn[2], smn[3]));
    mx = fmaxf(fmaxf(smx[0], smx[1]), fmaxf(smx[2], smx[3]));
    atomicMin(&ws[W_MINK + b], fkey(mn));
    atomicMax(&ws[W_MAXK + b], fkey(mx));
  }
}

// 16 blocks per batch: joint 512-halfbin x target-class histogram (1024 bins).
// scale512 = 2*scale256 makes idx512>>1 bit-identical to the reference 256-bin index.
__global__ __launch_bounds__(256) void k_hist(const float* __restrict__ x,
                                              const float* __restrict__ tg,
                                              uint32_t* __restrict__ ws) {
  __shared__ uint32_t h[NCB];
  const int t = threadIdx.x;
  h[t] = 0; h[t + 256] = 0; h[t + 512] = 0; h[t + 768] = 0;
  const int b = blockIdx.x >> 4;
  const int blk = blockIdx.x & 15;
  const float pmin = sigmoidf(funkey(ws[W_MINK + b]));
  const float pmax = sigmoidf(funkey(ws[W_MAXK + b]));
  const float span = pmax - pmin;
  const float scale256 = (span > 0.0f) ? (256.0f / span) : 0.0f;
  const float scale512 = 2.0f * scale256;
  __syncthreads();
  const size_t base = (size_t)b * NPB + (size_t)blk * (NPB / 16);
  const float4* px = reinterpret_cast<const float4*>(x + base);
  const float4* pt = reinterpret_cast<const float4*>(tg + base);
#pragma unroll 4
  for (int i = 0; i < 16; ++i) {
    float4 v = px[i * 256 + t];
    float4 w = pt[i * 256 + t];
#define PUT(a, c) { float fv = (sigmoidf(a) - pmin) * scale512;          \
                    int idx = (int)fv;                                    \
                    idx = idx < 0 ? 0 : (idx > 511 ? 511 : idx);          \
                    if ((c) > 0.5f) idx += 512;                           \
                    atomicAdd(&h[idx], 1u); }
    PUT(v.x, w.x) PUT(v.y, w.y) PUT(v.z, w.z) PUT(v.w, w.w)
#undef PUT
  }
  __syncthreads();
  uint32_t* g = ws + W_HIST + b * NCB;
#pragma unroll
  for (int i = t; i < NCB; i += 256)
    if (h[i]) atomicAdd(&g[i], h[i]);
}

// One 256-thread block per batch: parallel Otsu + IoU counts from the histogram.
__global__ __launch_bounds__(256) void k_otsu(uint32_t* __restrict__ ws) {
  __shared__ uint32_t hc[NCB];
  __shared__ uint32_t w1s[256];
  __shared__ float s1s[256];
  __shared__ float vv[256];
  __shared__ int vi[256];
  __shared__ unsigned long long redL[256];
  const int b = blockIdx.x;
  const int t = threadIdx.x;
  const uint32_t* H = ws + W_HIST + b * NCB;
  hc[t] = H[t]; hc[t + 256] = H[t + 256]; hc[t + 512] = H[t + 512]; hc[t + 768] = H[t + 768];
  const float pmin = sigmoidf(funkey(ws[W_MINK + b]));
  const float pmax = sigmoidf(funkey(ws[W_MAXK + b]));
  const float span = pmax - pmin;
  const float binw = span * (1.0f / 256.0f);   // == span/NBINS (pow2 divide, exact)
  __syncthreads();
  // per-thread slices of the histogram (hc stays intact throughout)
  const uint32_t a0 = hc[2 * t] + hc[2 * t + 512];          // all @ halfbin 2t
  const uint32_t a1 = hc[2 * t + 1] + hc[2 * t + 513];      // all @ halfbin 2t+1
  const uint32_t p0 = hc[2 * t + 512], p1 = hc[2 * t + 513]; // target-positive
  const uint32_t hk = a0 + a1;                              // reference 256-bin hist[t]
  const float ck = pmin + ((float)t + 0.5f) * binw;         // centers[t]
  w1s[t] = hk;
  s1s[t] = (float)hk * ck;
  // Hillis-Steele inclusive scans (w1 exact: integer counts < 2^24)
  for (int off = 1; off < 256; off <<= 1) {
    __syncthreads();
    uint32_t wp = (t >= off) ? w1s[t - off] : 0u;
    float    sp = (t >= off) ? s1s[t - off] : 0.0f;
    __syncthreads();
    w1s[t] += wp; s1s[t] += sp;
  }
  __syncthreads();
  const uint32_t totW = w1s[255];
  const float totS = s1s[255];
  float v = -INFINITY;
  if (t < 255) {
    const float w1f = (float)w1s[t];
    const float w2f = (float)(totW - w1s[t]);   // exact suffix weight from t+1
    const float m1 = s1s[t] / w1f;              // w1>=1 (min elem in bin 0)
    const float m2 = (totS - s1s[t]) / w2f;     // w2>=1 (max elem in bin 255)
    const float d = m1 - m2;
    v = (w1f * w2f) * (d * d);
  }
  vv[t] = v; vi[t] = t;
  // argmax, first-occurrence tie-break (matches np.argmax)
  for (int s = 128; s; s >>= 1) {
    __syncthreads();
    if (t < s) {
      const float vb = vv[t + s]; const int ib = vi[t + s];
      if (vb > vv[t] || (vb == vv[t] && ib < vi[t])) { vv[t] = vb; vi[t] = ib; }
    }
  }
  __syncthreads();
  const int J = 2 * vi[0] + 1;   // threshold = halfbin boundary at index J
  // packed masked suffix sums: nb | ni<<20 | nt<<40 (each total < 2^19)
  const uint32_t nb_p = ((2 * t) >= J ? a0 : 0u) + ((2 * t + 1) >= J ? a1 : 0u);
  const uint32_t ni_p = ((2 * t) >= J ? p0 : 0u) + ((2 * t + 1) >= J ? p1 : 0u);
  const uint32_t nt_p = p0 + p1;
  redL[t] = (unsigned long long)nb_p | ((unsigned long long)ni_p << 20) | ((unsigned long long)nt_p << 40);
  for (int s = 128; s; s >>= 1) {
    __syncthreads();
    if (t < s) redL[t] += redL[t + s];
  }
  __syncthreads();
  if (t == 0) {
    const unsigned long long P = redL[0];
    const float nb = (float)(uint32_t)(P & 0xFFFFFu);
    const float ni = (float)(uint32_t)((P >> 20) & 0xFFFFFu);
    const float nt = (float)(uint32_t)((P >> 40) & 0xFFFFFu);
    const float uni = nb + nt - ni;
    reinterpret_cast<float*>(ws)[W_IOU + b] = (ni + 1.0f) / (uni + 1.0f);
  }
}

__global__ __launch_bounds__(64) void k_final(const uint32_t* __restrict__ ws,
                                              float* __restrict__ out) {
  const int t = threadIdx.x;  // one wave, one lane per batch
  float iou = reinterpret_cast<const float*>(ws)[W_IOU + t];
  for (int off = 32; off; off >>= 1) iou += __shfl_down(iou, off);
  if (t == 0) out[0] = iou * (1.0f / 64.0f);
}

extern "C" void kernel_launch(void* const* d_in, const int* in_sizes, int n_in,
                              void* d_out, int out_size, void* d_ws, size_t ws_size,
                              hipStream_t stream) {
  const float* x  = (const float*)d_in[0];   // logits (64,1,512,512)
  const float* tg = (const float*)d_in[1];   // target (64,1,512,512)
  uint32_t* ws = (uint32_t*)d_ws;
  float* out = (float*)d_out;

  hipLaunchKernelGGL(k_init,   dim3((W_END + 255) / 256), dim3(256), 0, stream, ws);
  hipLaunchKernelGGL(k_minmax, dim3(BATCH * 16), dim3(256), 0, stream, x, ws);
  hipLaunchKernelGGL(k_hist,   dim3(BATCH * 16), dim3(256), 0, stream, x, tg, ws);
  hipLaunchKernelGGL(k_otsu,   dim3(BATCH),      dim3(256), 0, stream, ws);
  hipLaunchKernelGGL(k_final,  dim3(1),          dim3(64),  0, stream, ws, out);
}

// Round 3
// 43.592 us; speedup vs baseline: 2.6933x; 1.2653x over previous
//
#include <hip/hip_runtime.h>
#include <cstdint>

static constexpr int BATCH = 64;
static constexpr int NPB   = 512 * 512;   // elements per batch
static constexpr int NCB   = 1024;        // 512 half-bins x 2 target classes
static constexpr int HBLK  = 16;          // hist blocks per batch

// d_ws layout in 32-bit words (no init kernel needed: everything written before read):
static constexpr int W_BMIN  = 0;                        // 64*16 floats, per-block min
static constexpr int W_BMAX  = 1024;                     // 64*16 floats, per-block max
static constexpr int W_HPART = 2048;                     // 64*16*1024 uint partial hists (4 MiB)
static constexpr int W_IOU   = W_HPART + BATCH * HBLK * NCB;  // 64 floats

__device__ __forceinline__ float sigmoidf(float v) {   // precise: for pmin/pmax/centers
  if (v >= 0.0f) return 1.0f / (1.0f + expf(-v));
  float e = expf(v);
  return e / (1.0f + e);
}
__device__ __forceinline__ float fsig(float v) {       // fast: per-element binning only
  return __builtin_amdgcn_rcpf(1.0f + __expf(-v));
}

// 16 blocks per batch: per-block min/max of raw logits (sigmoid is monotone). No atomics.
__global__ __launch_bounds__(256) void k_minmax(const float* __restrict__ x,
                                                float* __restrict__ wsf) {
  const int b = blockIdx.x >> 4;
  const int blk = blockIdx.x & 15;
  const int t = threadIdx.x;
  const float4* p = reinterpret_cast<const float4*>(x + (size_t)b * NPB + (size_t)blk * (NPB / 16));
  float mn = INFINITY, mx = -INFINITY;
#pragma unroll
  for (int i = 0; i < 16; ++i) {
    float4 v = p[i * 256 + t];
    mn = fminf(mn, fminf(fminf(v.x, v.y), fminf(v.z, v.w)));
    mx = fmaxf(mx, fmaxf(fmaxf(v.x, v.y), fmaxf(v.z, v.w)));
  }
  for (int off = 32; off; off >>= 1) {
    mn = fminf(mn, __shfl_down(mn, off));
    mx = fmaxf(mx, __shfl_down(mx, off));
  }
  __shared__ float smn[4], smx[4];
  if ((t & 63) == 0) { smn[t >> 6] = mn; smx[t >> 6] = mx; }
  __syncthreads();
  if (t == 0) {
    wsf[W_BMIN + blockIdx.x] = fminf(fminf(smn[0], smn[1]), fminf(smn[2], smn[3]));
    wsf[W_BMAX + blockIdx.x] = fmaxf(fmaxf(smx[0], smx[1]), fmaxf(smx[2], smx[3]));
  }
}

// 16 blocks per batch: joint 512-halfbin x target-class histogram, per-wave LDS replicas,
// per-block partial written to its own global slot (no global atomics).
__global__ __launch_bounds__(256) void k_hist(const float* __restrict__ x,
                                              const float* __restrict__ tg,
                                              uint32_t* __restrict__ ws) {
  __shared__ uint32_t h[4 * NCB];
  __shared__ float sPmin, sScale;
  const int t = threadIdx.x;
  const int b = blockIdx.x >> 4;
  const int blk = blockIdx.x & 15;
  const float* wsf = reinterpret_cast<const float*>(ws);
  // reduce the 16 per-block min/max (first wave only does useful work)
  float mnv = (t < 16) ? wsf[W_BMIN + (b << 4) + t] : INFINITY;
  float mxv = (t < 16) ? wsf[W_BMAX + (b << 4) + t] : -INFINITY;
  for (int off = 8; off; off >>= 1) {
    mnv = fminf(mnv, __shfl_down(mnv, off));
    mxv = fmaxf(mxv, __shfl_down(mxv, off));
  }
  if (t == 0) {
    const float pmin = sigmoidf(mnv);
    const float pmax = sigmoidf(mxv);
    const float span = pmax - pmin;
    sPmin = pmin;
    sScale = (span > 0.0f) ? (512.0f / span) : 0.0f;  // == 2*(256/span) bit-exactly
  }
  // zero the 4 wave-replica histograms
  const uint4 z = {0u, 0u, 0u, 0u};
  reinterpret_cast<uint4*>(h)[t]       = z;
  reinterpret_cast<uint4*>(h)[t + 256] = z;
  reinterpret_cast<uint4*>(h)[t + 512] = z;
  reinterpret_cast<uint4*>(h)[t + 768] = z;
  __syncthreads();
  const float pmin = sPmin, scale = sScale;
  const uint32_t woff = (uint32_t)(t >> 6) << 10;   // wave-replica base
  const size_t base = (size_t)b * NPB + (size_t)blk * (NPB / 16);
  const float4* px = reinterpret_cast<const float4*>(x + base);
  const float4* pt = reinterpret_cast<const float4*>(tg + base);
#pragma unroll 4
  for (int i = 0; i < 16; ++i) {
    float4 v = px[i * 256 + t];
    float4 w = pt[i * 256 + t];
#define PUT(a, c) { float fv = (fsig(a) - pmin) * scale;                  \
                    int idx = (int)fv;                                     \
                    idx = idx < 0 ? 0 : (idx > 511 ? 511 : idx);           \
                    idx += ((c) > 0.5f) ? 512 : 0;                         \
                    atomicAdd(&h[woff + idx], 1u); }
    PUT(v.x, w.x) PUT(v.y, w.y) PUT(v.z, w.z) PUT(v.w, w.w)
#undef PUT
  }
  __syncthreads();
  // merge 4 replicas -> per-block partial hist slot (coalesced, no atomics)
  uint32_t* g = ws + W_HPART + (size_t)blockIdx.x * NCB;
#pragma unroll
  for (int j = 0; j < 4; ++j) {
    const int i = t + j * 256;
    g[i] = h[i] + h[i + 1024] + h[i + 2048] + h[i + 3072];
  }
}

// One 256-thread block per batch: sum partials, parallel Otsu + IoU from the histogram.
__global__ __launch_bounds__(256) void k_otsu(uint32_t* __restrict__ ws) {
  __shared__ uint32_t hc[NCB];
  __shared__ uint32_t w1s[256];
  __shared__ float s1s[256];
  __shared__ float vv[256];
  __shared__ int vi[256];
  __shared__ unsigned long long redL[256];
  __shared__ float sPmin, sBinw;
  const int b = blockIdx.x;
  const int t = threadIdx.x;
  const float* wsf = reinterpret_cast<const float*>(ws);
  float mnv = (t < 16) ? wsf[W_BMIN + (b << 4) + t] : INFINITY;
  float mxv = (t < 16) ? wsf[W_BMAX + (b << 4) + t] : -INFINITY;
  for (int off = 8; off; off >>= 1) {
    mnv = fminf(mnv, __shfl_down(mnv, off));
    mxv = fmaxf(mxv, __shfl_down(mxv, off));
  }
  if (t == 0) {
    const float pmin = sigmoidf(mnv);
    const float pmax = sigmoidf(mxv);
    sPmin = pmin;
    sBinw = (pmax - pmin) * (1.0f / 256.0f);   // span/NBINS (pow2, exact)
  }
  // sum the 16 partial hists: thread t owns bins 4t..4t+3 (uint4)
  uint4 acc = {0u, 0u, 0u, 0u};
#pragma unroll
  for (int p = 0; p < HBLK; ++p) {
    const uint4 v = reinterpret_cast<const uint4*>(ws + W_HPART + (size_t)((b << 4) + p) * NCB)[t];
    acc.x += v.x; acc.y += v.y; acc.z += v.z; acc.w += v.w;
  }
  reinterpret_cast<uint4*>(hc)[t] = acc;
  __syncthreads();
  const float pmin = sPmin, binw = sBinw;
  // per-thread slices (hc intact throughout)
  const uint32_t a0 = hc[2 * t] + hc[2 * t + 512];
  const uint32_t a1 = hc[2 * t + 1] + hc[2 * t + 513];
  const uint32_t p0 = hc[2 * t + 512], p1 = hc[2 * t + 513];
  const uint32_t hk = a0 + a1;                       // reference 256-bin hist[t]
  const float ck = pmin + ((float)t + 0.5f) * binw;  // centers[t]
  w1s[t] = hk;
  s1s[t] = (float)hk * ck;
  // Hillis-Steele inclusive scans (w1 exact: integer counts)
  for (int off = 1; off < 256; off <<= 1) {
    __syncthreads();
    uint32_t wp = (t >= off) ? w1s[t - off] : 0u;
    float    sp = (t >= off) ? s1s[t - off] : 0.0f;
    __syncthreads();
    w1s[t] += wp; s1s[t] += sp;
  }
  __syncthreads();
  const uint32_t totW = w1s[255];
  const float totS = s1s[255];
  float v = -INFINITY;
  if (t < 255) {
    const float w1f = (float)w1s[t];
    const float w2f = (float)(totW - w1s[t]);
    const float m1 = s1s[t] / w1f;
    const float m2 = (totS - s1s[t]) / w2f;
    const float d = m1 - m2;
    v = (w1f * w2f) * (d * d);
  }
  vv[t] = v; vi[t] = t;
  for (int s = 128; s; s >>= 1) {      // argmax, first-occurrence tie-break
    __syncthreads();
    if (t < s) {
      const float vb = vv[t + s]; const int ib = vi[t + s];
      if (vb > vv[t] || (vb == vv[t] && ib < vi[t])) { vv[t] = vb; vi[t] = ib; }
    }
  }
  __syncthreads();
  const int J = 2 * vi[0] + 1;         // threshold = half-bin boundary index
  const uint32_t nb_p = ((2 * t) >= J ? a0 : 0u) + ((2 * t + 1) >= J ? a1 : 0u);
  const uint32_t ni_p = ((2 * t) >= J ? p0 : 0u) + ((2 * t + 1) >= J ? p1 : 0u);
  const uint32_t nt_p = p0 + p1;
  redL[t] = (unsigned long long)nb_p | ((unsigned long long)ni_p << 20) | ((unsigned long long)nt_p << 40);
  for (int s = 128; s; s >>= 1) {
    __syncthreads();
    if (t < s) redL[t] += redL[t + s];
  }
  __syncthreads();
  if (t == 0) {
    const unsigned long long P = redL[0];
    const float nb = (float)(uint32_t)(P & 0xFFFFFu);
    const float ni = (float)(uint32_t)((P >> 20) & 0xFFFFFu);
    const float nt = (float)(uint32_t)((P >> 40) & 0xFFFFFu);
    const float uni = nb + nt - ni;
    reinterpret_cast<float*>(ws)[W_IOU + b] = (ni + 1.0f) / (uni + 1.0f);
  }
}

__global__ __launch_bounds__(64) void k_final(const uint32_t* __restrict__ ws,
                                              float* __restrict__ out) {
  const int t = threadIdx.x;  // one wave, one lane per batch
  float iou = reinterpret_cast<const float*>(ws)[W_IOU + t];
  for (int off = 32; off; off >>= 1) iou += __shfl_down(iou, off);
  if (t == 0) out[0] = iou * (1.0f / 64.0f);
}

extern "C" void kernel_launch(void* const* d_in, const int* in_sizes, int n_in,
                              void* d_out, int out_size, void* d_ws, size_t ws_size,
                              hipStream_t stream) {
  const float* x  = (const float*)d_in[0];   // logits (64,1,512,512)
  const float* tg = (const float*)d_in[1];   // target (64,1,512,512)
  uint32_t* ws = (uint32_t*)d_ws;
  float* out = (float*)d_out;

  hipLaunchKernelGGL(k_minmax, dim3(BATCH * 16), dim3(256), 0, stream,
                     x, reinterpret_cast<float*>(ws));
  hipLaunchKernelGGL(k_hist,   dim3(BATCH * 16), dim3(256), 0, stream, x, tg, ws);
  hipLaunchKernelGGL(k_otsu,   dim3(BATCH),      dim3(256), 0, stream, ws);
  hipLaunchKernelGGL(k_final,  dim3(1),          dim3(64),  0, stream, ws, out);
}